// Round 19
// baseline (271.196 us; speedup 1.0000x reference)
//
#include <hip/hip_runtime.h>
#include <cstddef>
#include <cstdint>
#include <math.h>

// Problem constants (B=1)
#define kS    2048
#define kDim  2048
#define kH    16
#define kG    2
#define kDH   128
#define kRep  8     // H / G
#define kL    32    // compression window
#define kDstr 16    // compression stride
#define kLP   32    // selection block
#define kNSel 16
#define kW    256   // sliding window
#define kJ    127   // (S - L)/D + 1
#define kNB   64    // S / LP
#define kScale 0.08838834764831845f
#define kQT   4     // queries per cmp_attn block
#define kQF   8     // queries per fused_attn block
#define kLDQ  2560  // qkv fused row stride (2048 q + 256 k + 256 v)

// LDS tile row strides (elements) — padded for conflict-free b128 reads
#define kKP   136   // K tile [32][136]
#define kVP   40    // V^T tile [128][40]

typedef __attribute__((ext_vector_type(4))) float f32x4;
typedef __attribute__((ext_vector_type(8))) __bf16 bf16x8;
typedef __attribute__((ext_vector_type(4))) __bf16 bf16x4;

__device__ __forceinline__ unsigned short f2bf(float f) {
  unsigned u = __float_as_uint(f);
  u += 0x7fff + ((u >> 16) & 1);   // RNE (finite values only)
  return (unsigned short)(u >> 16);
}

#define GLDS16(src, dst)                                                     \
  __builtin_amdgcn_global_load_lds(                                          \
      (const __attribute__((address_space(1))) unsigned int*)(src),          \
      (__attribute__((address_space(3))) unsigned int*)(dst), 16, 0, 0)

// ---------------------------------------------------------------------------
// f32 -> bf16 cast (contiguous, n4 = n/4)
// ---------------------------------------------------------------------------
__global__ void cast_bf16_kernel(const float* __restrict__ in,
                                 unsigned short* __restrict__ out, int n4) {
  int i = blockIdx.x * blockDim.x + threadIdx.x;
  if (i >= n4) return;
  float4 v = reinterpret_cast<const float4*>(in)[i];
  ushort4 o;
  o.x = f2bf(v.x); o.y = f2bf(v.y); o.z = f2bf(v.z); o.w = f2bf(v.w);
  reinterpret_cast<ushort4*>(out)[i] = o;
}

// ---------------------------------------------------------------------------
// transpose + cast: in[rows][cols] (row stride ldin) f32 -> out[cols][rows] bf16
// ---------------------------------------------------------------------------
__global__ __launch_bounds__(256) void transpose_cast_kernel(
    const float* __restrict__ in, int ldin, unsigned short* __restrict__ out,
    int rows, int cols) {
  __shared__ float tile[32][33];
  const int bx = blockIdx.x * 32;   // col
  const int by = blockIdx.y * 32;   // row
  const int tx = threadIdx.x & 31;
  const int ty = threadIdx.x >> 5;
#pragma unroll
  for (int i = 0; i < 32; i += 8)
    tile[ty + i][tx] = in[(size_t)(by + ty + i) * ldin + bx + tx];
  __syncthreads();
#pragma unroll
  for (int i = 0; i < 32; i += 8)
    out[(size_t)(bx + ty + i) * rows + by + tx] = f2bf(tile[tx][ty + i]);
}

// ---------------------------------------------------------------------------
// merged weight transposes: wq/wk/wv/wo -> bf16 transposed, one dispatch
// ---------------------------------------------------------------------------
__global__ __launch_bounds__(256) void transpose_weights_kernel(
    const float* __restrict__ wq, const float* __restrict__ wk,
    const float* __restrict__ wv, const float* __restrict__ wo,
    unsigned short* __restrict__ wqT, unsigned short* __restrict__ wkT,
    unsigned short* __restrict__ wvT, unsigned short* __restrict__ woT) {
  int b = blockIdx.x;
  const float* in;
  unsigned short* out;
  int rows, cols, rel;
  if (b < 4096)      { in = wq; out = wqT; rows = 2048; cols = 2048; rel = b; }
  else if (b < 4608) { in = wk; out = wkT; rows = 2048; cols = 256;  rel = b - 4096; }
  else if (b < 5120) { in = wv; out = wvT; rows = 2048; cols = 256;  rel = b - 4608; }
  else               { in = wo; out = woT; rows = 2048; cols = 2048; rel = b - 5120; }
  const int nbx = cols >> 5;
  const int bx = (rel % nbx) * 32;
  const int by = (rel / nbx) * 32;
  __shared__ float tile[32][33];
  const int tx = threadIdx.x & 31;
  const int ty = threadIdx.x >> 5;
#pragma unroll
  for (int i = 0; i < 32; i += 8)
    tile[ty + i][tx] = in[(size_t)(by + ty + i) * cols + bx + tx];
  __syncthreads();
#pragma unroll
  for (int i = 0; i < 32; i += 8)
    out[(size_t)(bx + ty + i) * rows + by + tx] = f2bf(tile[tx][ty + i]);
}

// ---------------------------------------------------------------------------
// bf16 MFMA GEMM v3: 64x128 tile, 512 threads / 8 waves (2x4 grid, each
// 32x32, acc 2x2). C[M][N] f32 (row stride ldc) = A[M][K] x Bt[N][K]^T
// ---------------------------------------------------------------------------
__global__ __launch_bounds__(512) void gemm_bf16_kernel(
    const unsigned short* __restrict__ A,
    const unsigned short* __restrict__ Bt,
    float* __restrict__ C, int M, int N, int ldc, int K) {
  __shared__ __align__(16) unsigned short As[64 * 32];    // 4 KB
  __shared__ __align__(16) unsigned short Bs[128 * 32];   // 8 KB
  const int t = threadIdx.x;
  const int lane = t & 63;
  const int wid = t >> 6;           // 0..7
  const int wr = wid >> 2;          // 0..1 : rows wr*32..+32
  const int wc = wid & 3;           // 0..3 : cols wc*32..+32
  const int lhi = lane >> 4, llo = lane & 15;
  const size_t row0 = (size_t)blockIdx.y * 64;
  const size_t col0 = (size_t)blockIdx.x * 128;

  f32x4 acc[2][2];
#pragma unroll
  for (int m = 0; m < 2; ++m)
#pragma unroll
    for (int n = 0; n < 2; ++n) acc[m][n] = f32x4{0.f, 0.f, 0.f, 0.f};

  const int ra = t >> 2, ka = (t & 3) * 8;   // A: slots 0..255 (t<256)
  const int rb = t >> 2, kb2 = (t & 3) * 8;  // B: slots 0..511 (all t)

  for (int k0 = 0; k0 < K; k0 += 32) {
    if (t < 256)
      GLDS16(A + (row0 + ra) * (size_t)K + k0 + ka, As + t * 8);
    GLDS16(Bt + (col0 + rb) * (size_t)K + k0 + kb2, Bs + t * 8);
    __syncthreads();
    bf16x8 af[2], bfr[2];
#pragma unroll
    for (int m = 0; m < 2; ++m)
      af[m] = *reinterpret_cast<const bf16x8*>(&As[(wr * 32 + m * 16 + llo) * 32 + lhi * 8]);
#pragma unroll
    for (int n = 0; n < 2; ++n)
      bfr[n] = *reinterpret_cast<const bf16x8*>(&Bs[(wc * 32 + n * 16 + llo) * 32 + lhi * 8]);
#pragma unroll
    for (int m = 0; m < 2; ++m)
#pragma unroll
      for (int n = 0; n < 2; ++n)
        acc[m][n] = __builtin_amdgcn_mfma_f32_16x16x32_bf16(af[m], bfr[n], acc[m][n], 0, 0, 0);
    __syncthreads();
  }
#pragma unroll
  for (int m = 0; m < 2; ++m)
#pragma unroll
    for (int n = 0; n < 2; ++n)
#pragma unroll
      for (int j = 0; j < 4; ++j) {
        size_t r = row0 + wr * 32 + m * 16 + lhi * 4 + j;
        size_t c = col0 + wc * 32 + n * 16 + llo;
        C[r * (size_t)ldc + c] = acc[m][n][j];
      }
}

// ---------------------------------------------------------------------------
// merged RoPE: q (cols 0..2048) then k (cols 2048..2304); in-place f32 +
// fused bf16 outputs. One dispatch.
// ---------------------------------------------------------------------------
__global__ void rope2_kernel(float* __restrict__ qkv,
                             const float* __restrict__ fc,
                             const float* __restrict__ fsn,
                             unsigned short* __restrict__ qb,
                             unsigned short* __restrict__ kb) {
  int idx = blockIdx.x * blockDim.x + threadIdx.x;
  const int totq = kS * kH * 64;
  float* tb;
  unsigned short* outb;
  int nheads, ldout;
  if (idx < totq) {
    tb = qkv; outb = qb; nheads = kH; ldout = kDim;
  } else {
    idx -= totq;
    tb = qkv + kDim; outb = kb; nheads = kG; ldout = kG * kDH;
  }
  int i = idx & 63;
  int h = (idx >> 6) % nheads;
  int s = idx / (64 * nheads);
  float c = fc[s * 64 + i];
  float sn = fsn[s * 64 + i];
  float* p = tb + (size_t)s * kLDQ + h * kDH + 2 * i;
  float x0 = p[0], x1 = p[1];
  float r0 = x0 * c - x1 * sn;
  float r1 = x0 * sn + x1 * c;
  p[0] = r0;
  p[1] = r1;
  unsigned short* o = outb + (size_t)s * ldout + h * kDH + 2 * i;
  o[0] = f2bf(r0);
  o[1] = f2bf(r1);
}

// ---------------------------------------------------------------------------
// Compression mean-pool: writes kcT f32 [g*128+d][128 j] and vcT bf16 same
// layout directly (transposed at production; j=127 zero-padded).
// ---------------------------------------------------------------------------
__global__ void pool_kernel(const float* __restrict__ qkv,
                            float* __restrict__ kcT,
                            unsigned short* __restrict__ vcT) {
  int idx = blockIdx.x * blockDim.x + threadIdx.x;
  if (idx >= 128 * kG * kDH) return;   // 32768
  int d = idx & 127;
  int g = (idx >> 7) & 1;
  int j = idx >> 8;                    // 0..127
  float sk = 0.f, sv = 0.f;
  if (j < kJ) {
    for (int l = 0; l < kL; ++l) {
      size_t row = (size_t)(j * kDstr + l) * kLDQ;
      sk += qkv[row + kDim + g * kDH + d];
      sv += qkv[row + kDim + kG * kDH + g * kDH + d];
    }
    sk *= (1.f / 32.f);
    sv *= (1.f / 32.f);
  }
  size_t o = ((size_t)(g * 128 + d)) * 128 + j;
  kcT[o] = sk;
  vcT[o] = f2bf(sv);
}

// ---------------------------------------------------------------------------
// cmp_attn v4 (round-12..18 verified)
// ---------------------------------------------------------------------------
__global__ __launch_bounds__(256) void cmp_attn_kernel(
    const float* __restrict__ qkv, const float* __restrict__ kcT,
    const unsigned short* __restrict__ vcT,
    const float* __restrict__ wg,
    float* __restrict__ oc, float* __restrict__ gates,
    unsigned long long* __restrict__ selmask) {
  __shared__ float qst[128][36];   // [d][row]
  __shared__ float pT [128][36];   // [j][row]
  __shared__ __align__(16) char ubuf[32 * 132 * 4];  // kvt f32 U pTb bf16
  float (*kvt)[132] = reinterpret_cast<float(*)[132]>(ubuf);
  unsigned short (*pTb)[136] = reinterpret_cast<unsigned short(*)[136]>(ubuf);

  const int b = blockIdx.x;
  const int g = b & 1;
  const int s0 = (b >> 1) * kQT;
  const int t = threadIdx.x;
  const int ty = t >> 5;
  const int tx = t & 31;

  {
    int row = t & 31;
    int dl = (t >> 5) * 16;
    const float* src = qkv + (size_t)(s0 + (row >> 3)) * kLDQ +
                       (g * kRep + (row & 7)) * kDH + dl;
#pragma unroll
    for (int i = 0; i < 4; ++i) {
      float4 v = *reinterpret_cast<const float4*>(src + i * 4);
      qst[dl + i * 4 + 0][row] = v.x;
      qst[dl + i * 4 + 1][row] = v.y;
      qst[dl + i * 4 + 2][row] = v.z;
      qst[dl + i * 4 + 3][row] = v.w;
    }
  }
  __syncthreads();

  float S[4][4];
#pragma unroll
  for (int rr = 0; rr < 4; ++rr)
#pragma unroll
    for (int jj = 0; jj < 4; ++jj) S[rr][jj] = 0.f;

  for (int dt = 0; dt < 4; ++dt) {
    {
      const float* base = kcT + (size_t)(g * 128 + dt * 32) * 128;
#pragma unroll
      for (int i = 0; i < 4; ++i) {
        int s = t + i * 256;
        int dd = s >> 5;
        int j4 = s & 31;
        *reinterpret_cast<float4*>(&kvt[dd][j4 * 4]) =
            *reinterpret_cast<const float4*>(base + dd * 128 + j4 * 4);
      }
    }
    __syncthreads();
#pragma unroll
    for (int kk = 0; kk < 32; ++kk) {
      float4 a = *reinterpret_cast<const float4*>(&qst[dt * 32 + kk][ty * 4]);
      float4 bb = *reinterpret_cast<const float4*>(&kvt[kk][tx * 4]);
      float av[4] = {a.x, a.y, a.z, a.w};
      float bv[4] = {bb.x, bb.y, bb.z, bb.w};
#pragma unroll
      for (int rr = 0; rr < 4; ++rr)
#pragma unroll
        for (int jj = 0; jj < 4; ++jj)
          S[rr][jj] = fmaf(av[rr], bv[jj], S[rr][jj]);
    }
    __syncthreads();
  }

#pragma unroll
  for (int rr = 0; rr < 4; ++rr) {
    int row = ty * 4 + rr;
    int s = s0 + (row >> 3);
    int jmax = (s >= kL - 1) ? ((s - (kL - 1)) >> 4) : -1;
#pragma unroll
    for (int jj = 0; jj < 4; ++jj) {
      int j = tx * 4 + jj;
      pT[j][row] = (j <= jmax && j < kJ) ? S[rr][jj] * kScale : -1e30f;
    }
  }
  __syncthreads();

  {
    int row = t >> 3;
    int l = t & 7;
    int s = s0 + (row >> 3);
    if (s < kL - 1) {
#pragma unroll
      for (int i = 0; i < 16; ++i) pT[l + i * 8][row] = 0.f;
    } else {
      float vals[16];
      float mx = -INFINITY;
#pragma unroll
      for (int i = 0; i < 16; ++i) {
        vals[i] = pT[l + i * 8][row];
        mx = fmaxf(mx, vals[i]);
      }
      mx = fmaxf(mx, __shfl_xor(mx, 1));
      mx = fmaxf(mx, __shfl_xor(mx, 2));
      mx = fmaxf(mx, __shfl_xor(mx, 4));
      float sm = 0.f;
#pragma unroll
      for (int i = 0; i < 16; ++i) {
        vals[i] = __expf(vals[i] - mx);
        sm += vals[i];
      }
      sm += __shfl_xor(sm, 1);
      sm += __shfl_xor(sm, 2);
      sm += __shfl_xor(sm, 4);
      float inv = 1.f / sm;
#pragma unroll
      for (int i = 0; i < 16; ++i) pT[l + i * 8][row] = vals[i] * inv;
    }
  }
  __syncthreads();   // pT final; kvt dead -> pTb may overwrite

  {
    int row = t >> 3;
    int l = t & 7;
#pragma unroll
    for (int i = 0; i < 16; ++i)
      pTb[row][l + i * 8] = f2bf(pT[l + i * 8][row]);
  }
  {
    int qq = t >> 6;
    int m = t & 63;
    int s = s0 + qq;
    int mcur = s >> 5;
    float im;
    if (m > mcur) {
      im = -INFINITY;
    } else {
      im = 0.f;
#pragma unroll
      for (int r = 0; r < 8; ++r) {
        int row = qq * 8 + r;
        float sp = (2 * m - 1 >= 0) ? pT[2 * m - 1][row] : 0.f;
        sp += pT[2 * m][row];
        if (2 * m + 1 < kJ) sp += pT[2 * m + 1][row];
        im += sp;
      }
      if (m == 0) im += 1e9f;
      if (m == mcur) im += 1e9f;
    }
    bool taken = false;
    unsigned long long mask = 0ull;
    for (int it = 0; it < kNSel; ++it) {
      float cv = taken ? -INFINITY : im;
      int ci = taken ? 64 : m;
#pragma unroll
      for (int off = 1; off < 64; off <<= 1) {
        float ov = __shfl_xor(cv, off);
        int oi = __shfl_xor(ci, off);
        if (ov > cv || (ov == cv && oi < ci)) { cv = ov; ci = oi; }
      }
      mask |= 1ull << ci;
      if (m == ci) taken = true;
    }
    if (m == 0) selmask[(size_t)s * 2 + g] = mask;
  }
  if (t < 192) {
    int task = t >> 1;
    int p = t & 1;
    int row = task / 3;
    int e = task - row * 3;
    int sQ = s0 + (row >> 3);
    int r = row & 7;
    const float* qr = qkv + (size_t)sQ * kLDQ + (g * kRep + r) * kDH + p * 64;
    float acc = 0.f;
#pragma unroll
    for (int i = 0; i < 16; ++i) {
      float4 v = *reinterpret_cast<const float4*>(qr + i * 4);
      int d = p * 64 + i * 4;
      acc = fmaf(v.x, wg[d * 3 + e], acc);
      acc = fmaf(v.y, wg[(d + 1) * 3 + e], acc);
      acc = fmaf(v.z, wg[(d + 2) * 3 + e], acc);
      acc = fmaf(v.w, wg[(d + 3) * 3 + e], acc);
    }
    acc += __shfl_xor(acc, 1);
    if (p == 0)
      gates[((size_t)(sQ * 2 + g) * kRep + r) * 3 + e] = 1.f / (1.f + __expf(-acc));
  }
  __syncthreads();   // pTb visible

  {
    const int lane = t & 63;
    const int wv = t >> 6;
    const int lo = lane & 15, hi = lane >> 4;
    f32x4 acc[2][2];
#pragma unroll
    for (int rt = 0; rt < 2; ++rt)
#pragma unroll
      for (int dt2 = 0; dt2 < 2; ++dt2) acc[rt][dt2] = f32x4{0.f, 0.f, 0.f, 0.f};
#pragma unroll
    for (int ks = 0; ks < 4; ++ks) {
      bf16x8 pf[2], vf[2];
#pragma unroll
      for (int rt = 0; rt < 2; ++rt)
        pf[rt] = *reinterpret_cast<const bf16x8*>(&pTb[rt * 16 + lo][ks * 32 + hi * 8]);
#pragma unroll
      for (int dt2 = 0; dt2 < 2; ++dt2)
        vf[dt2] = *reinterpret_cast<const bf16x8*>(
            vcT + ((size_t)(g * 128 + wv * 32 + dt2 * 16 + lo)) * 128 + ks * 32 + hi * 8);
#pragma unroll
      for (int rt = 0; rt < 2; ++rt)
#pragma unroll
        for (int dt2 = 0; dt2 < 2; ++dt2)
          acc[rt][dt2] = __builtin_amdgcn_mfma_f32_16x16x32_bf16(vf[dt2], pf[rt], acc[rt][dt2], 0, 0, 0);
    }
#pragma unroll
    for (int rt = 0; rt < 2; ++rt) {
      int qrow = rt * 16 + lo;
      size_t base = ((size_t)(s0 + (qrow >> 3)) * kH + g * kRep + (qrow & 7)) * kDH;
#pragma unroll
      for (int dt2 = 0; dt2 < 2; ++dt2) {
        int d0 = wv * 32 + dt2 * 16 + hi * 4;
#pragma unroll
        for (int jj = 0; jj < 4; ++jj)
          oc[base + d0 + jj] = acc[rt][dt2][jj];
      }
    }
  }
}

// ---------------------------------------------------------------------------
// Fused flash attention v8: TWO 32-token subtiles per barrier interval.
// attn_tile3 math byte-identical (subtiles processed sequentially -> same
// online-softmax order). Buffers [dbuf][sub]; stage next pair while
// computing current pair. LDS ~81.2 KB (2 blocks/CU at grid 512).
// ---------------------------------------------------------------------------
template <int MODE>  // 0 = selected, 1 = sliding window
__device__ __forceinline__ void attn_tile3(
    const unsigned short* __restrict__ Ksb, const unsigned short* __restrict__ VTb,
    const bf16x8 (&qf)[4], __bf16* Psw,
    int tb, unsigned selw, int wv, int lo, int hi, int s0,
    f32x4 (&O)[8], float& mst, float& lst) {
  f32x4 S0 = f32x4{0.f, 0.f, 0.f, 0.f};
  f32x4 S1 = f32x4{0.f, 0.f, 0.f, 0.f};
  __builtin_amdgcn_s_setprio(1);
#pragma unroll
  for (int ds = 0; ds < 4; ++ds) {
    bf16x8 a0 = *reinterpret_cast<const bf16x8*>(&Ksb[lo * kKP + ds * 32 + hi * 8]);
    bf16x8 a1 = *reinterpret_cast<const bf16x8*>(&Ksb[(16 + lo) * kKP + ds * 32 + hi * 8]);
    S0 = __builtin_amdgcn_mfma_f32_16x16x32_bf16(a0, qf[ds], S0, 0, 0, 0);
    S1 = __builtin_amdgcn_mfma_f32_16x16x32_bf16(a1, qf[ds], S1, 0, 0, 0);
  }
  __builtin_amdgcn_s_setprio(0);
  const int qloc = wv * 2 + (lo >> 3);
  const int s_row = s0 + qloc;
  const bool selq = (MODE == 1) || (((selw >> qloc) & 1u) != 0);
  float sv[2][4];
#pragma unroll
  for (int j = 0; j < 4; ++j) { sv[0][j] = S0[j]; sv[1][j] = S1[j]; }
#pragma unroll
  for (int tf = 0; tf < 2; ++tf)
#pragma unroll
    for (int j = 0; j < 4; ++j) {
      int tok = tb + tf * 16 + hi * 4 + j;
      bool ok = selq && (tok <= s_row) && (MODE == 0 || tok > s_row - kW);
      sv[tf][j] = ok ? sv[tf][j] * kScale : -1e30f;
    }
  float pm = sv[0][0];
#pragma unroll
  for (int tf = 0; tf < 2; ++tf)
#pragma unroll
    for (int j = 0; j < 4; ++j) pm = fmaxf(pm, sv[tf][j]);
  pm = fmaxf(pm, __shfl_xor(pm, 16));
  pm = fmaxf(pm, __shfl_xor(pm, 32));
  if (__any(pm > mst + 8.f)) {       // defer-max: skip rescale within e^8
    float mn = fmaxf(mst, pm);
    float f = __expf(mst - mn);
#pragma unroll
    for (int df = 0; df < 8; ++df)
#pragma unroll
      for (int j = 0; j < 4; ++j) O[df][j] *= f;
    lst *= f;
    mst = mn;
  }
  float lacc = 0.f;
#pragma unroll
  for (int tf = 0; tf < 2; ++tf) {
    bf16x4 pk;
#pragma unroll
    for (int j = 0; j < 4; ++j) {
      float e = __expf(sv[tf][j] - mst);
      lacc += e;
      pk[j] = (__bf16)e;
    }
    *reinterpret_cast<bf16x4*>(&Psw[lo * 40 + tf * 16 + hi * 4]) = pk;
  }
  lst += lacc;
  bf16x8 pfrag = *reinterpret_cast<const bf16x8*>(&Psw[lo * 40 + hi * 8]);
  __builtin_amdgcn_s_setprio(1);
#pragma unroll
  for (int df = 0; df < 8; ++df) {
    bf16x8 vf = *reinterpret_cast<const bf16x8*>(&VTb[(df * 16 + lo) * kVP + hi * 8]);
    O[df] = __builtin_amdgcn_mfma_f32_16x16x32_bf16(vf, pfrag, O[df], 0, 0, 0);
  }
  __builtin_amdgcn_s_setprio(0);
}

__global__ __launch_bounds__(256) void fused_attn_kernel(
    const unsigned short* __restrict__ qb, const unsigned short* __restrict__ kb,
    const unsigned short* __restrict__ vT, const float* __restrict__ ocp,
    const float* __restrict__ gts,
    const unsigned long long* __restrict__ selmask,
    unsigned short* __restrict__ preb) {
  __shared__ __align__(16) unsigned short Ks[2][2][32 * kKP];    // 34.8 KB
  __shared__ __align__(16) unsigned short VTs[2][2][128 * kVP];  // 41.0 KB
  __shared__ __align__(16) __bf16 Ps[4][16 * 40];                // 5.1 KB
  __shared__ unsigned long long qm[kQF];
  __shared__ unsigned char selbits[kNB];
  __shared__ unsigned char tlist[kNB + 12];
  __shared__ int nsel_sh, ntiles_sh;

  const int bid = blockIdx.x;
  const int g = bid & 1;
  const int idx = bid >> 1;               // 0..255
  const int qt = (idx < 128) ? idx : 383 - idx;   // balance: j pairs 255-j
  const int s0 = qt * kQF;
  const int t = threadIdx.x;
  const int lane = t & 63;
  const int wv = t >> 6;
  const int lo = lane & 15, hi = lane >> 4;

  int kBase[3], vBase[3];
#pragma unroll
  for (int ii = 0; ii < 3; ++ii) {
    int s = t + ii * 256;
    int r = s / 17, c = s - r * 17;
    if (c > 15) c = 0;
    kBase[ii] = r * 256 + g * 128 + c * 8;
    int r2 = s / 5, c2 = s - r2 * 5;
    if (c2 > 3) c2 = 0;
    vBase[ii] = (g * 128 + r2) * 2048 + c2 * 8;
  }
  auto STAGE = [&](int tb, unsigned short* Ksb, unsigned short* VTb) {
#pragma unroll
    for (int ii = 0; ii < 3; ++ii) {
      if (ii < 2 || t < 32)
        GLDS16(kb + (size_t)tb * 256 + kBase[ii], Ksb + (t + ii * 256) * 8);
      if (ii < 2 || t < 128)
        GLDS16(vT + (size_t)vBase[ii] + tb, VTb + (t + ii * 256) * 8);
    }
  };

  const int qrow = wv * 16 + lo;
  const int s_q = s0 + (qrow >> 3);
  const int hd = qrow & 7;
  bf16x8 qf[4];
  float g0v, g1v, g2v;
  {
    const unsigned short* src = qb + ((size_t)s_q * 16 + g * 8 + hd) * 128 + hi * 8;
#pragma unroll
    for (int ds = 0; ds < 4; ++ds)
      qf[ds] = *reinterpret_cast<const bf16x8*>(src + ds * 32);
    const float* gp = gts + ((size_t)(s_q * 2 + g) * 8 + hd) * 3;
    g0v = gp[0]; g1v = gp[1]; g2v = gp[2];
  }
  if (t < kQF) {
    int sQ = s0 + t;
    unsigned long long mm = selmask[(size_t)sQ * 2 + g];
    mm &= ((2ull << (sQ >> 5)) - 1ull);
    qm[t] = mm;
  }
  __syncthreads();
  if (t < kNB) {
    unsigned b = 0;
    for (int ql = 0; ql < kQF; ++ql)
      b |= (unsigned)((qm[ql] >> t) & 1ull) << ql;
    selbits[t] = (unsigned char)b;
  }
  if (t == 0) {
    unsigned long long u = 0;
    for (int ql = 0; ql < kQF; ++ql) u |= qm[ql];
    int n = 0;
    for (int m = 0; m < kNB; ++m)
      if ((u >> m) & 1ull) tlist[n++] = (unsigned char)m;
    nsel_sh = n;
    int hi_t = s0 >> 5;
    int lo_t = (s0 > 255) ? ((s0 - 255) >> 5) : 0;
    for (int tt = hi_t; tt >= lo_t; --tt) tlist[n++] = (unsigned char)tt;
    ntiles_sh = n;
  }
  __syncthreads();

  __bf16* Psw = &Ps[wv][0];
  const int nsel = nsel_sh;
  const int NT = ntiles_sh;     // >= 2 (forced block 0 + >= 1 sliding)

  f32x4 O1[8], O2[8];
#pragma unroll
  for (int df = 0; df < 8; ++df) {
    O1[df] = f32x4{0.f, 0.f, 0.f, 0.f};
    O2[df] = f32x4{0.f, 0.f, 0.f, 0.f};
  }
  float mst = -INFINITY, lst = 0.f;

  // process subtile i (sequential order preserved)
  auto PROCESS = [&](int i, const unsigned short* Ksb, const unsigned short* VTb) {
    int tb = (int)tlist[i] * 32;
    if (i < nsel) {
      attn_tile3<0>(Ksb, VTb, qf, Psw, tb, selbits[tlist[i]], wv, lo, hi, s0,
                    O1, mst, lst);
      if (i == nsel - 1) {   // finalize pass 1 (register-only)
        float lt = lst;
        lt += __shfl_xor(lt, 16);
        lt += __shfl_xor(lt, 32);
        float f = g1v / lt;
#pragma unroll
        for (int df = 0; df < 8; ++df)
#pragma unroll
          for (int j = 0; j < 4; ++j) O1[df][j] *= f;
        mst = -INFINITY;
        lst = 0.f;
      }
    } else {
      attn_tile3<1>(Ksb, VTb, qf, Psw, tb, 0u, wv, lo, hi, s0, O2, mst, lst);
    }
  };

  // prologue: stage pair 0
  int cur = 0;
  STAGE((int)tlist[0] * 32, Ks[0][0], VTs[0][0]);
  if (1 < NT) STAGE((int)tlist[1] * 32, Ks[0][1], VTs[0][1]);
  __syncthreads();
  for (int base = 0; base < NT; base += 2) {
    if (base + 2 < NT)
      STAGE((int)tlist[base + 2] * 32, Ks[cur ^ 1][0], VTs[cur ^ 1][0]);
    if (base + 3 < NT)
      STAGE((int)tlist[base + 3] * 32, Ks[cur ^ 1][1], VTs[cur ^ 1][1]);
    PROCESS(base, Ks[cur][0], VTs[cur][0]);
    if (base + 1 < NT)
      PROCESS(base + 1, Ks[cur][1], VTs[cur][1]);
    __syncthreads();
    cur ^= 1;
  }

  // ---- combine: g0*o_cmp + o_sel(scaled) + g2/l * o_sw -> bf16 ----
  {
    float lt = lst;
    lt += __shfl_xor(lt, 16);
    lt += __shfl_xor(lt, 32);
    float f2 = g2v / lt;
    size_t base = ((size_t)s_q * 16 + g * 8 + hd) * 128;
#pragma unroll
    for (int df = 0; df < 8; ++df) {
      int d0 = df * 16 + hi * 4;
      float4 ocv = *reinterpret_cast<const float4*>(&ocp[base + d0]);
      ushort4 w;
      w.x = f2bf(g0v * ocv.x + O1[df][0] + f2 * O2[df][0]);
      w.y = f2bf(g0v * ocv.y + O1[df][1] + f2 * O2[df][1]);
      w.z = f2bf(g0v * ocv.z + O1[df][2] + f2 * O2[df][2]);
      w.w = f2bf(g0v * ocv.w + O1[df][3] + f2 * O2[df][3]);
      *reinterpret_cast<ushort4*>(&preb[base + d0]) = w;
    }
  }
}

// ---------------------------------------------------------------------------
extern "C" void kernel_launch(void* const* d_in, const int* in_sizes, int n_in,
                              void* d_out, int out_size, void* d_ws, size_t ws_size,
                              hipStream_t stream) {
  (void)in_sizes; (void)n_in; (void)out_size; (void)ws_size;
  const float* x  = (const float*)d_in[0];
  const float* fc = (const float*)d_in[1];
  const float* fs = (const float*)d_in[2];
  const float* wq = (const float*)d_in[3];
  const float* wk = (const float*)d_in[4];
  const float* wv = (const float*)d_in[5];
  const float* wo = (const float*)d_in[6];
  const float* wg = (const float*)d_in[7];
  float* out = (float*)d_out;

  float* qkv  = (float*)d_ws;                    // [2048][2560] f32
  float* kcT  = qkv + (size_t)kS * kLDQ;         // [256][128] f32
  float* oc   = kcT + 256 * 128;                 // 4194304
  float* gts  = oc + kS * kH * kDH;              // 98304
  unsigned long long* selmask = (unsigned long long*)(gts + kS * kG * kRep * 3); // 4096
  unsigned short* xb   = (unsigned short*)(selmask + kS * kG);
  unsigned short* wqT  = xb + kS * kDim;           // wqkvT part 1: [2048][2048]
  unsigned short* wkT  = wqT + (kH * kDH) * kDim;  // wqkvT part 2: [256][2048]
  unsigned short* wvT  = wkT + (kG * kDH) * kDim;  // wqkvT part 3: [256][2048]
  unsigned short* woT  = wvT + (kG * kDH) * kDim;  // [2048][2048]
  unsigned short* preb = woT + kDim * (kH * kDH);  // [2048][2048]
  unsigned short* kb   = preb + kS * kDim;         // [2048 tok][2 g][128 d]
  unsigned short* vT   = kb + kS * kG * kDH;       // [2 g * 128 d][2048 tok]
  unsigned short* vcTb = vT + kS * kG * kDH;       // [256 dg][128 j]
  unsigned short* qbuf = xb;   // alias: xb dead after projection GEMM

  dim3 blk256(256);
  dim3 blk512(512);
  cast_bf16_kernel<<<kS * kDim / 4 / 256, blk256, 0, stream>>>(x, xb, kS * kDim / 4);
  // merged weight transposes (wq 4096 + wk 512 + wv 512 + wo 4096 tiles)
  transpose_weights_kernel<<<9216, blk256, 0, stream>>>(
      wq, wk, wv, wo, wqT, wkT, wvT, woT);
  // fused QKV projection: C = qkv[2048][2560]  (M64 tiles -> grid 640)
  gemm_bf16_kernel<<<dim3(kLDQ / 128, kS / 64), blk512, 0, stream>>>(
      xb, wqT, qkv, kS, kLDQ, kLDQ, kDim);
  // merged rope (q + k) with fused bf16 outputs
  rope2_kernel<<<(kS * kH * 64 + kS * kG * 64) / 256, blk256, 0, stream>>>(
      qkv, fc, fs, qbuf, kb);
  // V^T bf16 view
  transpose_cast_kernel<<<dim3(kG * kDH / 32, kS / 32), blk256, 0, stream>>>(
      qkv + kDim + kG * kDH, kLDQ, vT, kS, kG * kDH);
  pool_kernel<<<128, blk256, 0, stream>>>(qkv, kcT, vcTb);
  cmp_attn_kernel<<<kS / kQT * kG, blk256, 0, stream>>>(qkv, kcT, vcTb, wg, oc, gts, selmask);
  fused_attn_kernel<<<kS / kQF * kG, blk256, 0, stream>>>(qbuf, kb, vT, oc, gts, selmask, preb);
  // output projection (M64 tiles -> grid 512)
  gemm_bf16_kernel<<<dim3(kDim / 128, kS / 64), blk512, 0, stream>>>(
      preb, woT, out, kS, kDim, kDim, kH * kDH);
}

// Round 20
// 247.738 us; speedup vs baseline: 1.0947x; 1.0947x over previous
//
#include <hip/hip_runtime.h>
#include <cstddef>
#include <cstdint>
#include <math.h>

// Problem constants (B=1)
#define kS    2048
#define kDim  2048
#define kH    16
#define kG    2
#define kDH   128
#define kRep  8     // H / G
#define kL    32    // compression window
#define kDstr 16    // compression stride
#define kLP   32    // selection block
#define kNSel 16
#define kW    256   // sliding window
#define kJ    127   // (S - L)/D + 1
#define kNB   64    // S / LP
#define kScale 0.08838834764831845f
#define kQT   4     // queries per cmp_attn block
#define kQF   8     // queries per fused_attn block
#define kLDQ  2560  // qkv fused row stride (2048 q + 256 k + 256 v)

// LDS tile row strides (elements) — padded for conflict-free b128 reads
#define kKP   136   // K tile [32][136]
#define kVP   40    // V^T tile [128][40]

typedef __attribute__((ext_vector_type(4))) float f32x4;
typedef __attribute__((ext_vector_type(8))) __bf16 bf16x8;
typedef __attribute__((ext_vector_type(4))) __bf16 bf16x4;

__device__ __forceinline__ unsigned short f2bf(float f) {
  unsigned u = __float_as_uint(f);
  u += 0x7fff + ((u >> 16) & 1);   // RNE (finite values only)
  return (unsigned short)(u >> 16);
}

#define GLDS16(src, dst)                                                     \
  __builtin_amdgcn_global_load_lds(                                          \
      (const __attribute__((address_space(1))) unsigned int*)(src),          \
      (__attribute__((address_space(3))) unsigned int*)(dst), 16, 0, 0)

// ---------------------------------------------------------------------------
// f32 -> bf16 cast (contiguous, n4 = n/4)
// ---------------------------------------------------------------------------
__global__ void cast_bf16_kernel(const float* __restrict__ in,
                                 unsigned short* __restrict__ out, int n4) {
  int i = blockIdx.x * blockDim.x + threadIdx.x;
  if (i >= n4) return;
  float4 v = reinterpret_cast<const float4*>(in)[i];
  ushort4 o;
  o.x = f2bf(v.x); o.y = f2bf(v.y); o.z = f2bf(v.z); o.w = f2bf(v.w);
  reinterpret_cast<ushort4*>(out)[i] = o;
}

// ---------------------------------------------------------------------------
// transpose + cast: in[rows][cols] (row stride ldin) f32 -> out[cols][rows] bf16
// ---------------------------------------------------------------------------
__global__ __launch_bounds__(256) void transpose_cast_kernel(
    const float* __restrict__ in, int ldin, unsigned short* __restrict__ out,
    int rows, int cols) {
  __shared__ float tile[32][33];
  const int bx = blockIdx.x * 32;   // col
  const int by = blockIdx.y * 32;   // row
  const int tx = threadIdx.x & 31;
  const int ty = threadIdx.x >> 5;
#pragma unroll
  for (int i = 0; i < 32; i += 8)
    tile[ty + i][tx] = in[(size_t)(by + ty + i) * ldin + bx + tx];
  __syncthreads();
#pragma unroll
  for (int i = 0; i < 32; i += 8)
    out[(size_t)(bx + ty + i) * rows + by + tx] = f2bf(tile[tx][ty + i]);
}

// ---------------------------------------------------------------------------
// merged weight transposes: wq/wk/wv/wo -> bf16 transposed, one dispatch
// ---------------------------------------------------------------------------
__global__ __launch_bounds__(256) void transpose_weights_kernel(
    const float* __restrict__ wq, const float* __restrict__ wk,
    const float* __restrict__ wv, const float* __restrict__ wo,
    unsigned short* __restrict__ wqT, unsigned short* __restrict__ wkT,
    unsigned short* __restrict__ wvT, unsigned short* __restrict__ woT) {
  int b = blockIdx.x;
  const float* in;
  unsigned short* out;
  int rows, cols, rel;
  if (b < 4096)      { in = wq; out = wqT; rows = 2048; cols = 2048; rel = b; }
  else if (b < 4608) { in = wk; out = wkT; rows = 2048; cols = 256;  rel = b - 4096; }
  else if (b < 5120) { in = wv; out = wvT; rows = 2048; cols = 256;  rel = b - 4608; }
  else               { in = wo; out = woT; rows = 2048; cols = 2048; rel = b - 5120; }
  const int nbx = cols >> 5;
  const int bx = (rel % nbx) * 32;
  const int by = (rel / nbx) * 32;
  __shared__ float tile[32][33];
  const int tx = threadIdx.x & 31;
  const int ty = threadIdx.x >> 5;
#pragma unroll
  for (int i = 0; i < 32; i += 8)
    tile[ty + i][tx] = in[(size_t)(by + ty + i) * cols + bx + tx];
  __syncthreads();
#pragma unroll
  for (int i = 0; i < 32; i += 8)
    out[(size_t)(bx + ty + i) * rows + by + tx] = f2bf(tile[tx][ty + i]);
}

// ---------------------------------------------------------------------------
// bf16 MFMA GEMM v3: 64x128 tile, 512 threads / 8 waves (2x4 grid, each
// 32x32, acc 2x2). C[M][N] f32 (row stride ldc) = A[M][K] x Bt[N][K]^T
// ---------------------------------------------------------------------------
__global__ __launch_bounds__(512) void gemm_bf16_kernel(
    const unsigned short* __restrict__ A,
    const unsigned short* __restrict__ Bt,
    float* __restrict__ C, int M, int N, int ldc, int K) {
  __shared__ __align__(16) unsigned short As[64 * 32];    // 4 KB
  __shared__ __align__(16) unsigned short Bs[128 * 32];   // 8 KB
  const int t = threadIdx.x;
  const int lane = t & 63;
  const int wid = t >> 6;           // 0..7
  const int wr = wid >> 2;          // 0..1 : rows wr*32..+32
  const int wc = wid & 3;           // 0..3 : cols wc*32..+32
  const int lhi = lane >> 4, llo = lane & 15;
  const size_t row0 = (size_t)blockIdx.y * 64;
  const size_t col0 = (size_t)blockIdx.x * 128;

  f32x4 acc[2][2];
#pragma unroll
  for (int m = 0; m < 2; ++m)
#pragma unroll
    for (int n = 0; n < 2; ++n) acc[m][n] = f32x4{0.f, 0.f, 0.f, 0.f};

  const int ra = t >> 2, ka = (t & 3) * 8;   // A: slots 0..255 (t<256)
  const int rb = t >> 2, kb2 = (t & 3) * 8;  // B: slots 0..511 (all t)

  for (int k0 = 0; k0 < K; k0 += 32) {
    if (t < 256)
      GLDS16(A + (row0 + ra) * (size_t)K + k0 + ka, As + t * 8);
    GLDS16(Bt + (col0 + rb) * (size_t)K + k0 + kb2, Bs + t * 8);
    __syncthreads();
    bf16x8 af[2], bfr[2];
#pragma unroll
    for (int m = 0; m < 2; ++m)
      af[m] = *reinterpret_cast<const bf16x8*>(&As[(wr * 32 + m * 16 + llo) * 32 + lhi * 8]);
#pragma unroll
    for (int n = 0; n < 2; ++n)
      bfr[n] = *reinterpret_cast<const bf16x8*>(&Bs[(wc * 32 + n * 16 + llo) * 32 + lhi * 8]);
#pragma unroll
    for (int m = 0; m < 2; ++m)
#pragma unroll
      for (int n = 0; n < 2; ++n)
        acc[m][n] = __builtin_amdgcn_mfma_f32_16x16x32_bf16(af[m], bfr[n], acc[m][n], 0, 0, 0);
    __syncthreads();
  }
#pragma unroll
  for (int m = 0; m < 2; ++m)
#pragma unroll
    for (int n = 0; n < 2; ++n)
#pragma unroll
      for (int j = 0; j < 4; ++j) {
        size_t r = row0 + wr * 32 + m * 16 + lhi * 4 + j;
        size_t c = col0 + wc * 32 + n * 16 + llo;
        C[r * (size_t)ldc + c] = acc[m][n][j];
      }
}

// ---------------------------------------------------------------------------
// merged RoPE: q (cols 0..2048) then k (cols 2048..2304); in-place f32 +
// fused bf16 outputs. One dispatch.
// ---------------------------------------------------------------------------
__global__ void rope2_kernel(float* __restrict__ qkv,
                             const float* __restrict__ fc,
                             const float* __restrict__ fsn,
                             unsigned short* __restrict__ qb,
                             unsigned short* __restrict__ kb) {
  int idx = blockIdx.x * blockDim.x + threadIdx.x;
  const int totq = kS * kH * 64;
  float* tb;
  unsigned short* outb;
  int nheads, ldout;
  if (idx < totq) {
    tb = qkv; outb = qb; nheads = kH; ldout = kDim;
  } else {
    idx -= totq;
    tb = qkv + kDim; outb = kb; nheads = kG; ldout = kG * kDH;
  }
  int i = idx & 63;
  int h = (idx >> 6) % nheads;
  int s = idx / (64 * nheads);
  float c = fc[s * 64 + i];
  float sn = fsn[s * 64 + i];
  float* p = tb + (size_t)s * kLDQ + h * kDH + 2 * i;
  float x0 = p[0], x1 = p[1];
  float r0 = x0 * c - x1 * sn;
  float r1 = x0 * sn + x1 * c;
  p[0] = r0;
  p[1] = r1;
  unsigned short* o = outb + (size_t)s * ldout + h * kDH + 2 * i;
  o[0] = f2bf(r0);
  o[1] = f2bf(r1);
}

// ---------------------------------------------------------------------------
// Compression mean-pool: writes kcT f32 [g*128+d][128 j] and vcT bf16 same
// layout directly (transposed at production; j=127 zero-padded).
// ---------------------------------------------------------------------------
__global__ void pool_kernel(const float* __restrict__ qkv,
                            float* __restrict__ kcT,
                            unsigned short* __restrict__ vcT) {
  int idx = blockIdx.x * blockDim.x + threadIdx.x;
  if (idx >= 128 * kG * kDH) return;   // 32768
  int d = idx & 127;
  int g = (idx >> 7) & 1;
  int j = idx >> 8;                    // 0..127
  float sk = 0.f, sv = 0.f;
  if (j < kJ) {
    for (int l = 0; l < kL; ++l) {
      size_t row = (size_t)(j * kDstr + l) * kLDQ;
      sk += qkv[row + kDim + g * kDH + d];
      sv += qkv[row + kDim + kG * kDH + g * kDH + d];
    }
    sk *= (1.f / 32.f);
    sv *= (1.f / 32.f);
  }
  size_t o = ((size_t)(g * 128 + d)) * 128 + j;
  kcT[o] = sk;
  vcT[o] = f2bf(sv);
}

// ---------------------------------------------------------------------------
// cmp_attn v4 (round-12..18 verified)
// ---------------------------------------------------------------------------
__global__ __launch_bounds__(256) void cmp_attn_kernel(
    const float* __restrict__ qkv, const float* __restrict__ kcT,
    const unsigned short* __restrict__ vcT,
    const float* __restrict__ wg,
    float* __restrict__ oc, float* __restrict__ gates,
    unsigned long long* __restrict__ selmask) {
  __shared__ float qst[128][36];   // [d][row]
  __shared__ float pT [128][36];   // [j][row]
  __shared__ __align__(16) char ubuf[32 * 132 * 4];  // kvt f32 U pTb bf16
  float (*kvt)[132] = reinterpret_cast<float(*)[132]>(ubuf);
  unsigned short (*pTb)[136] = reinterpret_cast<unsigned short(*)[136]>(ubuf);

  const int b = blockIdx.x;
  const int g = b & 1;
  const int s0 = (b >> 1) * kQT;
  const int t = threadIdx.x;
  const int ty = t >> 5;
  const int tx = t & 31;

  {
    int row = t & 31;
    int dl = (t >> 5) * 16;
    const float* src = qkv + (size_t)(s0 + (row >> 3)) * kLDQ +
                       (g * kRep + (row & 7)) * kDH + dl;
#pragma unroll
    for (int i = 0; i < 4; ++i) {
      float4 v = *reinterpret_cast<const float4*>(src + i * 4);
      qst[dl + i * 4 + 0][row] = v.x;
      qst[dl + i * 4 + 1][row] = v.y;
      qst[dl + i * 4 + 2][row] = v.z;
      qst[dl + i * 4 + 3][row] = v.w;
    }
  }
  __syncthreads();

  float S[4][4];
#pragma unroll
  for (int rr = 0; rr < 4; ++rr)
#pragma unroll
    for (int jj = 0; jj < 4; ++jj) S[rr][jj] = 0.f;

  for (int dt = 0; dt < 4; ++dt) {
    {
      const float* base = kcT + (size_t)(g * 128 + dt * 32) * 128;
#pragma unroll
      for (int i = 0; i < 4; ++i) {
        int s = t + i * 256;
        int dd = s >> 5;
        int j4 = s & 31;
        *reinterpret_cast<float4*>(&kvt[dd][j4 * 4]) =
            *reinterpret_cast<const float4*>(base + dd * 128 + j4 * 4);
      }
    }
    __syncthreads();
#pragma unroll
    for (int kk = 0; kk < 32; ++kk) {
      float4 a = *reinterpret_cast<const float4*>(&qst[dt * 32 + kk][ty * 4]);
      float4 bb = *reinterpret_cast<const float4*>(&kvt[kk][tx * 4]);
      float av[4] = {a.x, a.y, a.z, a.w};
      float bv[4] = {bb.x, bb.y, bb.z, bb.w};
#pragma unroll
      for (int rr = 0; rr < 4; ++rr)
#pragma unroll
        for (int jj = 0; jj < 4; ++jj)
          S[rr][jj] = fmaf(av[rr], bv[jj], S[rr][jj]);
    }
    __syncthreads();
  }

#pragma unroll
  for (int rr = 0; rr < 4; ++rr) {
    int row = ty * 4 + rr;
    int s = s0 + (row >> 3);
    int jmax = (s >= kL - 1) ? ((s - (kL - 1)) >> 4) : -1;
#pragma unroll
    for (int jj = 0; jj < 4; ++jj) {
      int j = tx * 4 + jj;
      pT[j][row] = (j <= jmax && j < kJ) ? S[rr][jj] * kScale : -1e30f;
    }
  }
  __syncthreads();

  {
    int row = t >> 3;
    int l = t & 7;
    int s = s0 + (row >> 3);
    if (s < kL - 1) {
#pragma unroll
      for (int i = 0; i < 16; ++i) pT[l + i * 8][row] = 0.f;
    } else {
      float vals[16];
      float mx = -INFINITY;
#pragma unroll
      for (int i = 0; i < 16; ++i) {
        vals[i] = pT[l + i * 8][row];
        mx = fmaxf(mx, vals[i]);
      }
      mx = fmaxf(mx, __shfl_xor(mx, 1));
      mx = fmaxf(mx, __shfl_xor(mx, 2));
      mx = fmaxf(mx, __shfl_xor(mx, 4));
      float sm = 0.f;
#pragma unroll
      for (int i = 0; i < 16; ++i) {
        vals[i] = __expf(vals[i] - mx);
        sm += vals[i];
      }
      sm += __shfl_xor(sm, 1);
      sm += __shfl_xor(sm, 2);
      sm += __shfl_xor(sm, 4);
      float inv = 1.f / sm;
#pragma unroll
      for (int i = 0; i < 16; ++i) pT[l + i * 8][row] = vals[i] * inv;
    }
  }
  __syncthreads();   // pT final; kvt dead -> pTb may overwrite

  {
    int row = t >> 3;
    int l = t & 7;
#pragma unroll
    for (int i = 0; i < 16; ++i)
      pTb[row][l + i * 8] = f2bf(pT[l + i * 8][row]);
  }
  {
    int qq = t >> 6;
    int m = t & 63;
    int s = s0 + qq;
    int mcur = s >> 5;
    float im;
    if (m > mcur) {
      im = -INFINITY;
    } else {
      im = 0.f;
#pragma unroll
      for (int r = 0; r < 8; ++r) {
        int row = qq * 8 + r;
        float sp = (2 * m - 1 >= 0) ? pT[2 * m - 1][row] : 0.f;
        sp += pT[2 * m][row];
        if (2 * m + 1 < kJ) sp += pT[2 * m + 1][row];
        im += sp;
      }
      if (m == 0) im += 1e9f;
      if (m == mcur) im += 1e9f;
    }
    bool taken = false;
    unsigned long long mask = 0ull;
    for (int it = 0; it < kNSel; ++it) {
      float cv = taken ? -INFINITY : im;
      int ci = taken ? 64 : m;
#pragma unroll
      for (int off = 1; off < 64; off <<= 1) {
        float ov = __shfl_xor(cv, off);
        int oi = __shfl_xor(ci, off);
        if (ov > cv || (ov == cv && oi < ci)) { cv = ov; ci = oi; }
      }
      mask |= 1ull << ci;
      if (m == ci) taken = true;
    }
    if (m == 0) selmask[(size_t)s * 2 + g] = mask;
  }
  if (t < 192) {
    int task = t >> 1;
    int p = t & 1;
    int row = task / 3;
    int e = task - row * 3;
    int sQ = s0 + (row >> 3);
    int r = row & 7;
    const float* qr = qkv + (size_t)sQ * kLDQ + (g * kRep + r) * kDH + p * 64;
    float acc = 0.f;
#pragma unroll
    for (int i = 0; i < 16; ++i) {
      float4 v = *reinterpret_cast<const float4*>(qr + i * 4);
      int d = p * 64 + i * 4;
      acc = fmaf(v.x, wg[d * 3 + e], acc);
      acc = fmaf(v.y, wg[(d + 1) * 3 + e], acc);
      acc = fmaf(v.z, wg[(d + 2) * 3 + e], acc);
      acc = fmaf(v.w, wg[(d + 3) * 3 + e], acc);
    }
    acc += __shfl_xor(acc, 1);
    if (p == 0)
      gates[((size_t)(sQ * 2 + g) * kRep + r) * 3 + e] = 1.f / (1.f + __expf(-acc));
  }
  __syncthreads();   // pTb visible

  {
    const int lane = t & 63;
    const int wv = t >> 6;
    const int lo = lane & 15, hi = lane >> 4;
    f32x4 acc[2][2];
#pragma unroll
    for (int rt = 0; rt < 2; ++rt)
#pragma unroll
      for (int dt2 = 0; dt2 < 2; ++dt2) acc[rt][dt2] = f32x4{0.f, 0.f, 0.f, 0.f};
#pragma unroll
    for (int ks = 0; ks < 4; ++ks) {
      bf16x8 pf[2], vf[2];
#pragma unroll
      for (int rt = 0; rt < 2; ++rt)
        pf[rt] = *reinterpret_cast<const bf16x8*>(&pTb[rt * 16 + lo][ks * 32 + hi * 8]);
#pragma unroll
      for (int dt2 = 0; dt2 < 2; ++dt2)
        vf[dt2] = *reinterpret_cast<const bf16x8*>(
            vcT + ((size_t)(g * 128 + wv * 32 + dt2 * 16 + lo)) * 128 + ks * 32 + hi * 8);
#pragma unroll
      for (int rt = 0; rt < 2; ++rt)
#pragma unroll
        for (int dt2 = 0; dt2 < 2; ++dt2)
          acc[rt][dt2] = __builtin_amdgcn_mfma_f32_16x16x32_bf16(vf[dt2], pf[rt], acc[rt][dt2], 0, 0, 0);
    }
#pragma unroll
    for (int rt = 0; rt < 2; ++rt) {
      int qrow = rt * 16 + lo;
      size_t base = ((size_t)(s0 + (qrow >> 3)) * kH + g * kRep + (qrow & 7)) * kDH;
#pragma unroll
      for (int dt2 = 0; dt2 < 2; ++dt2) {
        int d0 = wv * 32 + dt2 * 16 + hi * 4;
#pragma unroll
        for (int jj = 0; jj < 4; ++jj)
          oc[base + d0 + jj] = acc[rt][dt2][jj];
      }
    }
  }
}

// ---------------------------------------------------------------------------
// Fused flash attention (round-18 verified: kQF=8, 256 thr, grid 512,
// qt work-balance remap, double-buffered __syncthreads, defer-max, setprio;
// prologue simplified: selmask read directly, no qm[] round-trip)
// ---------------------------------------------------------------------------
template <int MODE>  // 0 = selected, 1 = sliding window
__device__ __forceinline__ void attn_tile3(
    const unsigned short* __restrict__ Ksb, const unsigned short* __restrict__ VTb,
    const bf16x8 (&qf)[4], __bf16* Psw,
    int tb, unsigned selw, int wv, int lo, int hi, int s0,
    f32x4 (&O)[8], float& mst, float& lst) {
  f32x4 S0 = f32x4{0.f, 0.f, 0.f, 0.f};
  f32x4 S1 = f32x4{0.f, 0.f, 0.f, 0.f};
  __builtin_amdgcn_s_setprio(1);
#pragma unroll
  for (int ds = 0; ds < 4; ++ds) {
    bf16x8 a0 = *reinterpret_cast<const bf16x8*>(&Ksb[lo * kKP + ds * 32 + hi * 8]);
    bf16x8 a1 = *reinterpret_cast<const bf16x8*>(&Ksb[(16 + lo) * kKP + ds * 32 + hi * 8]);
    S0 = __builtin_amdgcn_mfma_f32_16x16x32_bf16(a0, qf[ds], S0, 0, 0, 0);
    S1 = __builtin_amdgcn_mfma_f32_16x16x32_bf16(a1, qf[ds], S1, 0, 0, 0);
  }
  __builtin_amdgcn_s_setprio(0);
  const int qloc = wv * 2 + (lo >> 3);
  const int s_row = s0 + qloc;
  const bool selq = (MODE == 1) || (((selw >> qloc) & 1u) != 0);
  float sv[2][4];
#pragma unroll
  for (int j = 0; j < 4; ++j) { sv[0][j] = S0[j]; sv[1][j] = S1[j]; }
#pragma unroll
  for (int tf = 0; tf < 2; ++tf)
#pragma unroll
    for (int j = 0; j < 4; ++j) {
      int tok = tb + tf * 16 + hi * 4 + j;
      bool ok = selq && (tok <= s_row) && (MODE == 0 || tok > s_row - kW);
      sv[tf][j] = ok ? sv[tf][j] * kScale : -1e30f;
    }
  float pm = sv[0][0];
#pragma unroll
  for (int tf = 0; tf < 2; ++tf)
#pragma unroll
    for (int j = 0; j < 4; ++j) pm = fmaxf(pm, sv[tf][j]);
  pm = fmaxf(pm, __shfl_xor(pm, 16));
  pm = fmaxf(pm, __shfl_xor(pm, 32));
  if (__any(pm > mst + 8.f)) {       // defer-max: skip rescale within e^8
    float mn = fmaxf(mst, pm);
    float f = __expf(mst - mn);
#pragma unroll
    for (int df = 0; df < 8; ++df)
#pragma unroll
      for (int j = 0; j < 4; ++j) O[df][j] *= f;
    lst *= f;
    mst = mn;
  }
  float lacc = 0.f;
#pragma unroll
  for (int tf = 0; tf < 2; ++tf) {
    bf16x4 pk;
#pragma unroll
    for (int j = 0; j < 4; ++j) {
      float e = __expf(sv[tf][j] - mst);
      lacc += e;
      pk[j] = (__bf16)e;
    }
    *reinterpret_cast<bf16x4*>(&Psw[lo * 40 + tf * 16 + hi * 4]) = pk;
  }
  lst += lacc;
  bf16x8 pfrag = *reinterpret_cast<const bf16x8*>(&Psw[lo * 40 + hi * 8]);
  __builtin_amdgcn_s_setprio(1);
#pragma unroll
  for (int df = 0; df < 8; ++df) {
    bf16x8 vf = *reinterpret_cast<const bf16x8*>(&VTb[(df * 16 + lo) * kVP + hi * 8]);
    O[df] = __builtin_amdgcn_mfma_f32_16x16x32_bf16(vf, pfrag, O[df], 0, 0, 0);
  }
  __builtin_amdgcn_s_setprio(0);
}

__global__ __launch_bounds__(256) void fused_attn_kernel(
    const unsigned short* __restrict__ qb, const unsigned short* __restrict__ kb,
    const unsigned short* __restrict__ vT, const float* __restrict__ ocp,
    const float* __restrict__ gts,
    const unsigned long long* __restrict__ selmask,
    unsigned short* __restrict__ preb) {
  __shared__ __align__(16) unsigned short Ks[2][32 * kKP];
  __shared__ __align__(16) unsigned short VTs[2][128 * kVP];
  __shared__ __align__(16) __bf16 Ps[4][16 * 40];
  __shared__ unsigned char selbits[kNB];
  __shared__ unsigned char blist[kNB];
  __shared__ int nsel_sh;

  const int bid = blockIdx.x;
  const int g = bid & 1;
  const int idx = bid >> 1;               // 0..255
  const int qt = (idx < 128) ? idx : 383 - idx;   // balance: j pairs 255-j
  const int s0 = qt * kQF;
  const int t = threadIdx.x;
  const int lane = t & 63;
  const int wv = t >> 6;
  const int lo = lane & 15, hi = lane >> 4;

  int kBase[3], vBase[3];
#pragma unroll
  for (int ii = 0; ii < 3; ++ii) {
    int s = t + ii * 256;
    int r = s / 17, c = s - r * 17;
    if (c > 15) c = 0;
    kBase[ii] = r * 256 + g * 128 + c * 8;
    int r2 = s / 5, c2 = s - r2 * 5;
    if (c2 > 3) c2 = 0;
    vBase[ii] = (g * 128 + r2) * 2048 + c2 * 8;
  }
  auto STAGE = [&](int tb, unsigned short* Ksb, unsigned short* VTb) {
#pragma unroll
    for (int ii = 0; ii < 3; ++ii) {
      if (ii < 2 || t < 32)
        GLDS16(kb + (size_t)tb * 256 + kBase[ii], Ksb + (t + ii * 256) * 8);
      if (ii < 2 || t < 128)
        GLDS16(vT + (size_t)vBase[ii] + tb, VTb + (t + ii * 256) * 8);
    }
  };

  const int qrow = wv * 16 + lo;
  const int s_q = s0 + (qrow >> 3);
  const int hd = qrow & 7;
  bf16x8 qf[4];
  {
    const unsigned short* src = qb + ((size_t)s_q * 16 + g * 8 + hd) * 128 + hi * 8;
#pragma unroll
    for (int ds = 0; ds < 4; ++ds)
      qf[ds] = *reinterpret_cast<const bf16x8*>(src + ds * 32);
  }
  // selection bit matrix + union list (selmask read directly; no qm round-trip)
  if (t < kNB) {
    unsigned b = 0;
    const unsigned long long* smp = selmask + (size_t)s0 * 2 + g;
#pragma unroll
    for (int ql = 0; ql < kQF; ++ql) {
      unsigned long long mm = smp[(size_t)ql * 2];
      mm &= ((2ull << ((s0 + ql) >> 5)) - 1ull);
      b |= (unsigned)((mm >> t) & 1ull) << ql;
    }
    selbits[t] = (unsigned char)b;
  }
  __syncthreads();
  if (t == 0) {
    int n = 0;
    for (int m = 0; m < kNB; ++m)
      if (selbits[m]) blist[n++] = (unsigned char)m;
    nsel_sh = n;
  }
  __syncthreads();

  __bf16* Psw = &Ps[wv][0];

  f32x4 O1[8], O2[8];
#pragma unroll
  for (int df = 0; df < 8; ++df) O1[df] = f32x4{0.f, 0.f, 0.f, 0.f};
  float mst = -INFINITY, lst = 0.f;

  const int nsel = nsel_sh;
  int cur = 0;
  STAGE((int)blist[0] * 32, Ks[0], VTs[0]);
  __syncthreads();
  for (int i = 0; i < nsel; ++i) {
    if (i + 1 < nsel)
      STAGE((int)blist[i + 1] * 32, Ks[cur ^ 1], VTs[cur ^ 1]);
    int b = blist[i];
    attn_tile3<0>(Ks[cur], VTs[cur], qf, Psw, b * 32, selbits[b], wv, lo, hi, s0,
                  O1, mst, lst);
    __syncthreads();
    cur ^= 1;
  }
  const int hi_t = s0 >> 5;
  const int lo_t = (s0 > 255) ? ((s0 - 255) >> 5) : 0;
  STAGE(hi_t * 32, Ks[cur], VTs[cur]);
  float g0v, g2v;
  {
    const float* gp = gts + ((size_t)(s_q * 2 + g) * 8 + hd) * 3;
    g0v = gp[0];
    g2v = gp[2];
    float lt = lst;
    lt += __shfl_xor(lt, 16);
    lt += __shfl_xor(lt, 32);
    float f = gp[1] / lt;
#pragma unroll
    for (int df = 0; df < 8; ++df)
#pragma unroll
      for (int j = 0; j < 4; ++j) O1[df][j] *= f;
  }
  mst = -INFINITY;
  lst = 0.f;
#pragma unroll
  for (int df = 0; df < 8; ++df) O2[df] = f32x4{0.f, 0.f, 0.f, 0.f};
  __syncthreads();

  for (int tt = hi_t; tt >= lo_t; --tt) {
    if (tt - 1 >= lo_t)
      STAGE((tt - 1) * 32, Ks[cur ^ 1], VTs[cur ^ 1]);
    attn_tile3<1>(Ks[cur], VTs[cur], qf, Psw, tt * 32, 0u, wv, lo, hi, s0,
                  O2, mst, lst);
    __syncthreads();
    cur ^= 1;
  }

  {
    float lt = lst;
    lt += __shfl_xor(lt, 16);
    lt += __shfl_xor(lt, 32);
    float f2 = g2v / lt;
    size_t base = ((size_t)s_q * 16 + g * 8 + hd) * 128;
#pragma unroll
    for (int df = 0; df < 8; ++df) {
      int d0 = df * 16 + hi * 4;
      float4 ocv = *reinterpret_cast<const float4*>(&ocp[base + d0]);
      ushort4 w;
      w.x = f2bf(g0v * ocv.x + O1[df][0] + f2 * O2[df][0]);
      w.y = f2bf(g0v * ocv.y + O1[df][1] + f2 * O2[df][1]);
      w.z = f2bf(g0v * ocv.z + O1[df][2] + f2 * O2[df][2]);
      w.w = f2bf(g0v * ocv.w + O1[df][3] + f2 * O2[df][3]);
      *reinterpret_cast<ushort4*>(&preb[base + d0]) = w;
    }
  }
}

// ---------------------------------------------------------------------------
extern "C" void kernel_launch(void* const* d_in, const int* in_sizes, int n_in,
                              void* d_out, int out_size, void* d_ws, size_t ws_size,
                              hipStream_t stream) {
  (void)in_sizes; (void)n_in; (void)out_size; (void)ws_size;
  const float* x  = (const float*)d_in[0];
  const float* fc = (const float*)d_in[1];
  const float* fs = (const float*)d_in[2];
  const float* wq = (const float*)d_in[3];
  const float* wk = (const float*)d_in[4];
  const float* wv = (const float*)d_in[5];
  const float* wo = (const float*)d_in[6];
  const float* wg = (const float*)d_in[7];
  float* out = (float*)d_out;

  float* qkv  = (float*)d_ws;                    // [2048][2560] f32
  float* kcT  = qkv + (size_t)kS * kLDQ;         // [256][128] f32
  float* oc   = kcT + 256 * 128;                 // 4194304
  float* gts  = oc + kS * kH * kDH;              // 98304
  unsigned long long* selmask = (unsigned long long*)(gts + kS * kG * kRep * 3); // 4096
  unsigned short* xb   = (unsigned short*)(selmask + kS * kG);
  unsigned short* wqT  = xb + kS * kDim;           // wqkvT part 1: [2048][2048]
  unsigned short* wkT  = wqT + (kH * kDH) * kDim;  // wqkvT part 2: [256][2048]
  unsigned short* wvT  = wkT + (kG * kDH) * kDim;  // wqkvT part 3: [256][2048]
  unsigned short* woT  = wvT + (kG * kDH) * kDim;  // [2048][2048]
  unsigned short* preb = woT + kDim * (kH * kDH);  // [2048][2048]
  unsigned short* kb   = preb + kS * kDim;         // [2048 tok][2 g][128 d]
  unsigned short* vT   = kb + kS * kG * kDH;       // [2 g * 128 d][2048 tok]
  unsigned short* vcTb = vT + kS * kG * kDH;       // [256 dg][128 j]
  unsigned short* qbuf = xb;   // alias: xb dead after projection GEMM

  dim3 blk256(256);
  dim3 blk512(512);
  cast_bf16_kernel<<<kS * kDim / 4 / 256, blk256, 0, stream>>>(x, xb, kS * kDim / 4);
  // merged weight transposes (wq 4096 + wk 512 + wv 512 + wo 4096 tiles)
  transpose_weights_kernel<<<9216, blk256, 0, stream>>>(
      wq, wk, wv, wo, wqT, wkT, wvT, woT);
  // fused QKV projection: C = qkv[2048][2560]  (M64 tiles -> grid 640)
  gemm_bf16_kernel<<<dim3(kLDQ / 128, kS / 64), blk512, 0, stream>>>(
      xb, wqT, qkv, kS, kLDQ, kLDQ, kDim);
  // merged rope (q + k) with fused bf16 outputs
  rope2_kernel<<<(kS * kH * 64 + kS * kG * 64) / 256, blk256, 0, stream>>>(
      qkv, fc, fs, qbuf, kb);
  // V^T bf16 view
  transpose_cast_kernel<<<dim3(kG * kDH / 32, kS / 32), blk256, 0, stream>>>(
      qkv + kDim + kG * kDH, kLDQ, vT, kS, kG * kDH);
  pool_kernel<<<128, blk256, 0, stream>>>(qkv, kcT, vcTb);
  cmp_attn_kernel<<<kS / kQT * kG, blk256, 0, stream>>>(qkv, kcT, vcTb, wg, oc, gts, selmask);
  fused_attn_kernel<<<kS / kQF * kG, blk256, 0, stream>>>(qbuf, kb, vT, oc, gts, selmask, preb);
  // output projection (M64 tiles -> grid 512)
  gemm_bf16_kernel<<<dim3(kDim / 128, kS / 64), blk512, 0, stream>>>(
      preb, woT, out, kS, kDim, kDim, kH * kDH);
}